// Round 7
// baseline (1122.280 us; speedup 1.0000x reference)
//
#include <hip/hip_runtime.h>
#include <cfloat>
#include <cmath>

#define NROWS 16384
#define DDIM  4096
#define NEXP  64
#define TOPK  8
#define GAP_THRESH 5e-4f

#define CHUNK  16                // k per LDS chunk
#define RB     128               // rows per block

// ws layout: [WdT 2MB][count 256B][list 64KB][part S*4MB]

// ---------------------------------------------------------------------------
// prep: WdT[k][e] = (double)W[e][k]  (fp64, transposed for coalesced fix
// loads), zero flag counter.
// ---------------------------------------------------------------------------
__global__ __launch_bounds__(256) void prep_kernel(const float* __restrict__ W,
                                                   double* __restrict__ WdT,
                                                   int* __restrict__ count) {
    int t = blockIdx.x * 256 + threadIdx.x;   // 0..262143
    int k = t >> 6, e = t & 63;
    WdT[t] = (double)W[(size_t)e * DDIM + k];
    if (t == 0) *count = 0;
}

// async 16B global->LDS (LDS dest = wave-uniform base + lane*16, linear)
__device__ __forceinline__ void gload_lds16(const float* g, float* l) {
    __builtin_amdgcn_global_load_lds(
        (const __attribute__((address_space(1))) unsigned int*)g,
        (__attribute__((address_space(3))) unsigned int*)l,
        16, 0, 0);
}

// ---------------------------------------------------------------------------
// Gate GEMM fp32.  Block = 128 thr (2 waves), tile 128 rows x 64 e.
// CHUNK=16 -> LDS 24KB -> 6 blocks/CU; launch_bounds(128,3) -> VGPR<=170 ->
// 3 waves/SIMD.  Runtime K-split S (grid = 128*S blocks).
// Thread = 8 rows x 8 experts = 64 acc; per quad 16 b128 per 256 FMA.
// Row stride in LDS = 64B: x read slot q^((tr>>1)&3) -> 2-way (free);
// w read slot q^(tc&3) -> conflict-free.  Swizzle applied on the GLOBAL
// source (rule #21), LDS dest stays linear for global_load_lds.
// ---------------------------------------------------------------------------
__global__ __launch_bounds__(128, 3) void gate_kernel(
    const float* __restrict__ x,
    const float* __restrict__ W,
    float* __restrict__ part,          // [S][NROWS][NEXP]
    int ksbits)
{
    __shared__ float xT[2][CHUNK * RB];    // 2 x 8 KB : 8 calls of 16 rows
    __shared__ float wT[2][CHUNK * NEXP];  // 2 x 4 KB : 4 calls of 16 experts

    const int t    = threadIdx.x;          // 0..127
    const int l    = t & 63;
    const int wv   = t >> 6;               // 0..1
    const int S    = 1 << ksbits;
    const int h    = blockIdx.x & (S - 1);
    const int row0 = (blockIdx.x >> ksbits) * RB;
    const int k0   = h << (12 - ksbits);   // h * (DDIM/S)
    const int nchunk = (DDIM >> ksbits) / CHUNK;

    const int lrow  = l >> 2;              // 0..15 row-in-call
    const int lslot = l & 3;               // 16B slot within 64B row

    // x staging: call c = wv*4+j covers rows 16c..16c+15.
    // LDS slot s of row r holds global col-group s ^ ((r>>1)&3).
    const int xcg = lslot ^ ((l >> 3) & 3);          // ((lrow>>1)&3)
    const float* gx[4];
#pragma unroll
    for (int j = 0; j < 4; ++j) {
        const int c = wv * 4 + j;
        gx[j] = x + (size_t)(row0 + c * 16 + lrow) * DDIM + k0 + xcg * 4;
    }
    // w staging: call c = wv*2+j covers experts 16c..16c+15.
    // LDS slot s of expert e holds col-group s ^ ((e>>3)&3).
    const float* gw[2];
#pragma unroll
    for (int j = 0; j < 2; ++j) {
        const int c = wv * 2 + j;
        const int wcg = lslot ^ ((2 * c + (l >> 5)) & 3);
        gw[j] = W + (size_t)(c * 16 + lrow) * DDIM + k0 + wcg * 4;
    }

#define STAGE(nb, koff) do {                                           \
        _Pragma("unroll")                                              \
        for (int j_ = 0; j_ < 4; ++j_)                                 \
            gload_lds16(gx[j_] + (koff), &xT[nb][(wv * 4 + j_) * 256]); \
        _Pragma("unroll")                                              \
        for (int j_ = 0; j_ < 2; ++j_)                                 \
            gload_lds16(gw[j_] + (koff), &wT[nb][(wv * 2 + j_) * 256]); \
    } while (0)

    // compute tile: rows tr+16*ri, experts tc*8+ei
    const int tr  = t & 15;
    const int tc  = t >> 4;                // 0..7
    const int xsw = (tr >> 1) & 3;
    const int wsw = tc & 3;
    int xo[4], wo[4];
#pragma unroll
    for (int q = 0; q < 4; ++q) {
        xo[q] = (q ^ xsw) << 2;
        wo[q] = (q ^ wsw) << 2;
    }

    float acc[8][8] = {};

    STAGE(0, 0);
    __syncthreads();

    int buf = 0;
    for (int c = 0; c < nchunk; ++c) {
        if (c + 1 < nchunk) STAGE(buf ^ 1, (c + 1) * CHUNK);  // async prefetch

        const float* xb = xT[buf];
        const float* wb = wT[buf];
#pragma unroll
        for (int q = 0; q < 4; ++q) {                 // 4 k per quad
            float4 wreg[8];
#pragma unroll
            for (int ei = 0; ei < 8; ++ei)
                wreg[ei] = *reinterpret_cast<const float4*>(
                    wb + (tc * 8 + ei) * 16 + wo[q]);
#pragma unroll
            for (int ri = 0; ri < 8; ++ri) {
                float4 xv = *reinterpret_cast<const float4*>(
                    xb + (tr + 16 * ri) * 16 + xo[q]);
#pragma unroll
                for (int ei = 0; ei < 8; ++ei) {
                    acc[ri][ei] = fmaf(xv.x, wreg[ei].x, acc[ri][ei]);
                    acc[ri][ei] = fmaf(xv.y, wreg[ei].y, acc[ri][ei]);
                    acc[ri][ei] = fmaf(xv.z, wreg[ei].z, acc[ri][ei]);
                    acc[ri][ei] = fmaf(xv.w, wreg[ei].w, acc[ri][ei]);
                }
            }
        }
        __syncthreads();
        buf ^= 1;
    }
#undef STAGE

#pragma unroll
    for (int ri = 0; ri < 8; ++ri) {
        const int row = row0 + tr + 16 * ri;
        float* pp = part + ((size_t)h * NROWS + row) * NEXP + tc * 8;
        *reinterpret_cast<float4*>(pp) =
            make_float4(acc[ri][0], acc[ri][1], acc[ri][2], acc[ri][3]);
        *reinterpret_cast<float4*>(pp + 4) =
            make_float4(acc[ri][4], acc[ri][5], acc[ri][6], acc[ri][7]);
    }
}

// ---------------------------------------------------------------------------
// Reduce + top-9 + sparse softmax + ambiguity flag (proven rounds 3-6).
// ---------------------------------------------------------------------------
__global__ __launch_bounds__(256) void reduce_kernel(
    const float* __restrict__ part,
    const float* __restrict__ b,
    float* __restrict__ outp,
    float* __restrict__ outi,
    int*   __restrict__ count,
    int*   __restrict__ list,
    int S)
{
    const int lane = threadIdx.x & 63;
    const int w    = threadIdx.x >> 6;
    const int row  = blockIdx.x * 4 + w;

    float orig = b[lane];
    for (int h = 0; h < S; ++h)
        orig += part[((size_t)h * NROWS + row) * NEXP + lane];

    float cur = orig;
    float vals[9];
    float myidxf = 0.0f;
    bool  sel = false;

#pragma unroll
    for (int i = 0; i < 9; ++i) {
        float m = cur;
#pragma unroll
        for (int off = 32; off > 0; off >>= 1)
            m = fmaxf(m, __shfl_xor(m, off, 64));
        unsigned long long msk = __ballot(cur == m);
        int il = __ffsll((long long)msk) - 1;
        vals[i] = m;
        if (lane == il) { cur = -FLT_MAX; if (i < TOPK) sel = true; }
        if (i < TOPK && lane == i) myidxf = (float)il;
    }

    float ssum = 0.0f;
#pragma unroll
    for (int i = 0; i < TOPK; ++i) ssum += expf(vals[i] - vals[0]);
    float p = sel ? (expf(orig - vals[0]) / ssum) : 0.0f;

    outp[(size_t)row * NEXP + lane] = p;
    if (lane < TOPK) outi[(size_t)row * TOPK + lane] = myidxf;

    float mingap = FLT_MAX;
#pragma unroll
    for (int i = 0; i < 8; ++i) mingap = fminf(mingap, vals[i] - vals[i + 1]);
    if (lane == 0 && mingap < GAP_THRESH) {
        int pos = atomicAdd(count, 1);
        if (pos < NROWS) list[pos] = row;
    }
}

// ---------------------------------------------------------------------------
// fp64 rescue.  x row staged in LDS (coalesced float4), WdT[k][e] reads are
// wave-coalesced 512B (round-6 Wd[e][k] reads fetched 64 lines/instr).
// ---------------------------------------------------------------------------
__global__ __launch_bounds__(64) void fix_kernel(
    const float*  __restrict__ x,
    const double* __restrict__ WdT,
    const float*  __restrict__ b,
    float* __restrict__ outp,
    float* __restrict__ outi,
    const int* __restrict__ count,
    const int* __restrict__ list)
{
    __shared__ float xs[DDIM];
    const int lane = threadIdx.x;
    const int cnt  = *count;

    for (int i = blockIdx.x; i < cnt; i += gridDim.x) {
        const int row = list[i];

        const float4* xr4 = reinterpret_cast<const float4*>(x + (size_t)row * DDIM);
#pragma unroll
        for (int j = 0; j < DDIM / 4 / 64; ++j)
            reinterpret_cast<float4*>(xs)[j * 64 + lane] = xr4[j * 64 + lane];
        __syncthreads();

        double a0 = 0.0, a1 = 0.0, a2 = 0.0, a3 = 0.0;
        for (int k = 0; k < DDIM; k += 4) {
            float4 xv = *reinterpret_cast<const float4*>(xs + k);   // broadcast
            a0 = fma((double)xv.x, WdT[(size_t)(k + 0) * NEXP + lane], a0);
            a1 = fma((double)xv.y, WdT[(size_t)(k + 1) * NEXP + lane], a1);
            a2 = fma((double)xv.z, WdT[(size_t)(k + 2) * NEXP + lane], a2);
            a3 = fma((double)xv.w, WdT[(size_t)(k + 3) * NEXP + lane], a3);
        }
        const double orig = ((a0 + a1) + (a2 + a3)) + (double)b[lane];
        double cur = orig;

        double vals[TOPK];
        float  myidxf = 0.0f;
        bool   sel = false;

#pragma unroll
        for (int tt = 0; tt < TOPK; ++tt) {
            double m = cur;
#pragma unroll
            for (int off = 32; off > 0; off >>= 1) {
                double o = __shfl_xor(m, off, 64);
                m = fmax(m, o);
            }
            unsigned long long msk = __ballot(cur == m);
            int il = __ffsll((long long)msk) - 1;
            vals[tt] = m;
            if (lane == il) { cur = -DBL_MAX; sel = true; }
            if (lane == tt)  myidxf = (float)il;
        }

        double ssum = 0.0;
#pragma unroll
        for (int tt = 0; tt < TOPK; ++tt) ssum += exp(vals[tt] - vals[0]);
        float p = sel ? (float)(exp(orig - vals[0]) / ssum) : 0.0f;

        outp[(size_t)row * NEXP + lane] = p;
        if (lane < TOPK) outi[(size_t)row * TOPK + lane] = myidxf;
        __syncthreads();   // xs reused next iteration
    }
}

// ---------------------------------------------------------------------------
// Fallback (tiny ws): per-thread-row full fp64 from f32 W.  Correct, slow.
// ---------------------------------------------------------------------------
__global__ __launch_bounds__(64) void fallback_kernel(
    const float* __restrict__ x,
    const float* __restrict__ W,
    const float* __restrict__ b,
    float* __restrict__ outp,
    float* __restrict__ outi)
{
    const int row = blockIdx.x * 64 + threadIdx.x;
    double lg[64];
#pragma unroll
    for (int e = 0; e < 64; ++e) lg[e] = (double)b[e];
    const float* xr = x + (size_t)row * DDIM;
    for (int k = 0; k < DDIM; k += 4) {
        float4 xa = *reinterpret_cast<const float4*>(xr + k);
        double xd[4] = {(double)xa.x, (double)xa.y, (double)xa.z, (double)xa.w};
#pragma unroll
        for (int e = 0; e < 64; ++e) {
            const float* wp = W + (size_t)e * DDIM + k;
            double a = lg[e];
#pragma unroll
            for (int j = 0; j < 4; ++j) a = fma(xd[j], (double)wp[j], a);
            lg[e] = a;
        }
    }
    unsigned long long selm = 0ull;
    double vals[TOPK]; int idx[TOPK];
#pragma unroll
    for (int i = 0; i < TOPK; ++i) {
        double m = -DBL_MAX; int mi = 0;
#pragma unroll
        for (int e = 0; e < 64; ++e) {
            bool gt = !((selm >> e) & 1ull) && (lg[e] > m);
            m = gt ? lg[e] : m; mi = gt ? e : mi;
        }
        vals[i] = m; idx[i] = mi; selm |= (1ull << mi);
    }
    double ssum = 0.0;
#pragma unroll
    for (int i = 0; i < TOPK; ++i) ssum += exp(vals[i] - vals[0]);
    double inv = 1.0 / ssum;
#pragma unroll
    for (int e = 0; e < 64; ++e)
        outp[(size_t)row * NEXP + e] =
            ((selm >> e) & 1ull) ? (float)(exp(lg[e] - vals[0]) * inv) : 0.0f;
#pragma unroll
    for (int i = 0; i < TOPK; ++i)
        outi[(size_t)row * TOPK + i] = (float)idx[i];
}

// ---------------------------------------------------------------------------
extern "C" void kernel_launch(void* const* d_in, const int* in_sizes, int n_in,
                              void* d_out, int out_size, void* d_ws, size_t ws_size,
                              hipStream_t stream) {
    (void)in_sizes; (void)n_in; (void)out_size;
    const float* x = (const float*)d_in[0];
    const float* W = (const float*)d_in[1];
    const float* b = (const float*)d_in[2];

    float* outp = (float*)d_out;
    float* outi = outp + (size_t)NROWS * NEXP;

    const size_t wd_bytes = sizeof(double) * (size_t)NEXP * DDIM;   // 2 MB
    const size_t cnt_off  = wd_bytes;
    const size_t list_off = cnt_off + 256;
    const size_t part_off = list_off + (size_t)NROWS * sizeof(int);

    int ksbits = -1;
    for (int kb = 4; kb >= 2; --kb) {   // S = 16, 8, 4
        size_t need = part_off + ((size_t)NROWS * NEXP * sizeof(float) << kb);
        if (ws_size >= need) { ksbits = kb; break; }
    }

    if (ksbits >= 0) {
        const int S = 1 << ksbits;
        double* WdT  = (double*)d_ws;
        int*    cnt  = (int*)((char*)d_ws + cnt_off);
        int*    list = (int*)((char*)d_ws + list_off);
        float*  part = (float*)((char*)d_ws + part_off);

        prep_kernel<<<(NEXP * DDIM) / 256, 256, 0, stream>>>(W, WdT, cnt);
        gate_kernel<<<(NROWS / RB) * S, 128, 0, stream>>>(x, W, part, ksbits);
        reduce_kernel<<<NROWS / 4, 256, 0, stream>>>(part, b, outp, outi, cnt, list, S);
        fix_kernel<<<1024, 64, 0, stream>>>(x, WdT, b, outp, outi, cnt, list);
    } else {
        fallback_kernel<<<NROWS / 64, 64, 0, stream>>>(x, W, b, outp, outi);
    }
}

// Round 8
// 339.070 us; speedup vs baseline: 3.3099x; 3.3099x over previous
//
#include <hip/hip_runtime.h>
#include <cfloat>
#include <cmath>

#define NROWS 16384
#define DDIM  4096
#define NEXP  64
#define TOPK  8
#define GAP_THRESH 5e-4f

#define CHUNK  16                // k per LDS chunk
#define RB     128               // rows per block

// ws layout: [WdT 2MB][count 256B][list 64KB][part S*4MB]

// ---------------------------------------------------------------------------
// prep: WdT[k][e] = (double)W[e][k]  (fp64, transposed for coalesced fix
// loads), zero flag counter.
// ---------------------------------------------------------------------------
__global__ __launch_bounds__(256) void prep_kernel(const float* __restrict__ W,
                                                   double* __restrict__ WdT,
                                                   int* __restrict__ count) {
    int t = blockIdx.x * 256 + threadIdx.x;   // 0..262143
    int k = t >> 6, e = t & 63;
    WdT[t] = (double)W[(size_t)e * DDIM + k];
    if (t == 0) *count = 0;
}

// async 16B global->LDS (LDS dest = wave-uniform base + lane*16, linear)
__device__ __forceinline__ void gload_lds16(const float* g, float* l) {
    __builtin_amdgcn_global_load_lds(
        (const __attribute__((address_space(1))) unsigned int*)g,
        (__attribute__((address_space(3))) unsigned int*)l,
        16, 0, 0);
}

// ---------------------------------------------------------------------------
// Gate GEMM fp32.  Block = 128 thr (2 waves), tile 128 rows x 64 e.
// CHUNK=16 -> LDS 24KB.  NO min-waves hint: round 7's (128,3) capped VGPR at
// 84 and spilled acc[8][8] in the inner loop (WRITE 2GB, VALUBusy 8%).
// Plain bounds -> ~152 VGPR (round-6-proven, no spill) -> 3 waves/SIMD
// VGPR-limited, 6 blocks/CU; grid = 128*S = 2048 supplies 8/CU.
// Thread = 8 rows x 8 experts = 64 acc; per quad 16 b128 per 256 FMA.
// x read slot q^((tr>>1)&3) -> 2-way (free) + 4-way broadcast; w read slot
// q^(tc&3) -> conflict-free + 16-way broadcast.  Swizzle applied on the
// GLOBAL source (rule #21), LDS dest stays linear for global_load_lds.
// ---------------------------------------------------------------------------
__global__ __launch_bounds__(128) void gate_kernel(
    const float* __restrict__ x,
    const float* __restrict__ W,
    float* __restrict__ part,          // [S][NROWS][NEXP]
    int ksbits)
{
    __shared__ float xT[2][CHUNK * RB];    // 2 x 8 KB : 8 calls of 16 rows
    __shared__ float wT[2][CHUNK * NEXP];  // 2 x 4 KB : 4 calls of 16 experts

    const int t    = threadIdx.x;          // 0..127
    const int l    = t & 63;
    const int wv   = t >> 6;               // 0..1
    const int S    = 1 << ksbits;
    const int h    = blockIdx.x & (S - 1);
    const int row0 = (blockIdx.x >> ksbits) * RB;
    const int k0   = h << (12 - ksbits);   // h * (DDIM/S)
    const int nchunk = (DDIM >> ksbits) / CHUNK;

    const int lrow  = l >> 2;              // 0..15 row-in-call
    const int lslot = l & 3;               // 16B slot within 64B row

    // x staging: call c = wv*4+j covers rows 16c..16c+15.
    // LDS slot s of row r holds global col-group s ^ ((r>>1)&3).
    const int xcg = lslot ^ ((l >> 3) & 3);          // ((lrow>>1)&3)
    const float* gx[4];
#pragma unroll
    for (int j = 0; j < 4; ++j) {
        const int c = wv * 4 + j;
        gx[j] = x + (size_t)(row0 + c * 16 + lrow) * DDIM + k0 + xcg * 4;
    }
    // w staging: call c = wv*2+j covers experts 16c..16c+15.
    // LDS slot s of expert e holds col-group s ^ ((e>>3)&3).
    const float* gw[2];
#pragma unroll
    for (int j = 0; j < 2; ++j) {
        const int c = wv * 2 + j;
        const int wcg = lslot ^ ((2 * c + (l >> 5)) & 3);
        gw[j] = W + (size_t)(c * 16 + lrow) * DDIM + k0 + wcg * 4;
    }

#define STAGE(nb, koff) do {                                           \
        _Pragma("unroll")                                              \
        for (int j_ = 0; j_ < 4; ++j_)                                 \
            gload_lds16(gx[j_] + (koff), &xT[nb][(wv * 4 + j_) * 256]); \
        _Pragma("unroll")                                              \
        for (int j_ = 0; j_ < 2; ++j_)                                 \
            gload_lds16(gw[j_] + (koff), &wT[nb][(wv * 2 + j_) * 256]); \
    } while (0)

    // compute tile: rows tr+16*ri, experts tc*8+ei
    const int tr  = t & 15;
    const int tc  = t >> 4;                // 0..7
    const int xsw = (tr >> 1) & 3;
    const int wsw = tc & 3;
    int xo[4], wo[4];
#pragma unroll
    for (int q = 0; q < 4; ++q) {
        xo[q] = (q ^ xsw) << 2;
        wo[q] = (q ^ wsw) << 2;
    }

    float acc[8][8] = {};

    STAGE(0, 0);
    __syncthreads();

    int buf = 0;
    for (int c = 0; c < nchunk; ++c) {
        if (c + 1 < nchunk) STAGE(buf ^ 1, (c + 1) * CHUNK);  // async prefetch

        const float* xb = xT[buf];
        const float* wb = wT[buf];
#pragma unroll
        for (int q = 0; q < 4; ++q) {                 // 4 k per quad
            float4 wreg[8];
#pragma unroll
            for (int ei = 0; ei < 8; ++ei)
                wreg[ei] = *reinterpret_cast<const float4*>(
                    wb + (tc * 8 + ei) * 16 + wo[q]);
#pragma unroll
            for (int ri = 0; ri < 8; ++ri) {
                float4 xv = *reinterpret_cast<const float4*>(
                    xb + (tr + 16 * ri) * 16 + xo[q]);
#pragma unroll
                for (int ei = 0; ei < 8; ++ei) {
                    acc[ri][ei] = fmaf(xv.x, wreg[ei].x, acc[ri][ei]);
                    acc[ri][ei] = fmaf(xv.y, wreg[ei].y, acc[ri][ei]);
                    acc[ri][ei] = fmaf(xv.z, wreg[ei].z, acc[ri][ei]);
                    acc[ri][ei] = fmaf(xv.w, wreg[ei].w, acc[ri][ei]);
                }
            }
        }
        __syncthreads();
        buf ^= 1;
    }
#undef STAGE

#pragma unroll
    for (int ri = 0; ri < 8; ++ri) {
        const int row = row0 + tr + 16 * ri;
        float* pp = part + ((size_t)h * NROWS + row) * NEXP + tc * 8;
        *reinterpret_cast<float4*>(pp) =
            make_float4(acc[ri][0], acc[ri][1], acc[ri][2], acc[ri][3]);
        *reinterpret_cast<float4*>(pp + 4) =
            make_float4(acc[ri][4], acc[ri][5], acc[ri][6], acc[ri][7]);
    }
}

// ---------------------------------------------------------------------------
// Reduce + top-9 + sparse softmax + ambiguity flag (proven rounds 3-7).
// ---------------------------------------------------------------------------
__global__ __launch_bounds__(256) void reduce_kernel(
    const float* __restrict__ part,
    const float* __restrict__ b,
    float* __restrict__ outp,
    float* __restrict__ outi,
    int*   __restrict__ count,
    int*   __restrict__ list,
    int S)
{
    const int lane = threadIdx.x & 63;
    const int w    = threadIdx.x >> 6;
    const int row  = blockIdx.x * 4 + w;

    float orig = b[lane];
    for (int h = 0; h < S; ++h)
        orig += part[((size_t)h * NROWS + row) * NEXP + lane];

    float cur = orig;
    float vals[9];
    float myidxf = 0.0f;
    bool  sel = false;

#pragma unroll
    for (int i = 0; i < 9; ++i) {
        float m = cur;
#pragma unroll
        for (int off = 32; off > 0; off >>= 1)
            m = fmaxf(m, __shfl_xor(m, off, 64));
        unsigned long long msk = __ballot(cur == m);
        int il = __ffsll((long long)msk) - 1;
        vals[i] = m;
        if (lane == il) { cur = -FLT_MAX; if (i < TOPK) sel = true; }
        if (i < TOPK && lane == i) myidxf = (float)il;
    }

    float ssum = 0.0f;
#pragma unroll
    for (int i = 0; i < TOPK; ++i) ssum += expf(vals[i] - vals[0]);
    float p = sel ? (expf(orig - vals[0]) / ssum) : 0.0f;

    outp[(size_t)row * NEXP + lane] = p;
    if (lane < TOPK) outi[(size_t)row * TOPK + lane] = myidxf;

    float mingap = FLT_MAX;
#pragma unroll
    for (int i = 0; i < 8; ++i) mingap = fminf(mingap, vals[i] - vals[i + 1]);
    if (lane == 0 && mingap < GAP_THRESH) {
        int pos = atomicAdd(count, 1);
        if (pos < NROWS) list[pos] = row;
    }
}

// ---------------------------------------------------------------------------
// fp64 rescue.  x row staged in LDS (coalesced float4); WdT[k][e] reads are
// wave-coalesced 512B.
// ---------------------------------------------------------------------------
__global__ __launch_bounds__(64) void fix_kernel(
    const float*  __restrict__ x,
    const double* __restrict__ WdT,
    const float*  __restrict__ b,
    float* __restrict__ outp,
    float* __restrict__ outi,
    const int* __restrict__ count,
    const int* __restrict__ list)
{
    __shared__ float xs[DDIM];
    const int lane = threadIdx.x;
    const int cnt  = *count;

    for (int i = blockIdx.x; i < cnt; i += gridDim.x) {
        const int row = list[i];

        const float4* xr4 = reinterpret_cast<const float4*>(x + (size_t)row * DDIM);
#pragma unroll
        for (int j = 0; j < DDIM / 4 / 64; ++j)
            reinterpret_cast<float4*>(xs)[j * 64 + lane] = xr4[j * 64 + lane];
        __syncthreads();

        double a0 = 0.0, a1 = 0.0, a2 = 0.0, a3 = 0.0;
        for (int k = 0; k < DDIM; k += 4) {
            float4 xv = *reinterpret_cast<const float4*>(xs + k);   // broadcast
            a0 = fma((double)xv.x, WdT[(size_t)(k + 0) * NEXP + lane], a0);
            a1 = fma((double)xv.y, WdT[(size_t)(k + 1) * NEXP + lane], a1);
            a2 = fma((double)xv.z, WdT[(size_t)(k + 2) * NEXP + lane], a2);
            a3 = fma((double)xv.w, WdT[(size_t)(k + 3) * NEXP + lane], a3);
        }
        const double orig = ((a0 + a1) + (a2 + a3)) + (double)b[lane];
        double cur = orig;

        double vals[TOPK];
        float  myidxf = 0.0f;
        bool   sel = false;

#pragma unroll
        for (int tt = 0; tt < TOPK; ++tt) {
            double m = cur;
#pragma unroll
            for (int off = 32; off > 0; off >>= 1) {
                double o = __shfl_xor(m, off, 64);
                m = fmax(m, o);
            }
            unsigned long long msk = __ballot(cur == m);
            int il = __ffsll((long long)msk) - 1;
            vals[tt] = m;
            if (lane == il) { cur = -DBL_MAX; sel = true; }
            if (lane == tt)  myidxf = (float)il;
        }

        double ssum = 0.0;
#pragma unroll
        for (int tt = 0; tt < TOPK; ++tt) ssum += exp(vals[tt] - vals[0]);
        float p = sel ? (float)(exp(orig - vals[0]) / ssum) : 0.0f;

        outp[(size_t)row * NEXP + lane] = p;
        if (lane < TOPK) outi[(size_t)row * TOPK + lane] = myidxf;
        __syncthreads();   // xs reused next iteration
    }
}

// ---------------------------------------------------------------------------
// Fallback (tiny ws): per-thread-row full fp64 from f32 W.  Correct, slow.
// ---------------------------------------------------------------------------
__global__ __launch_bounds__(64) void fallback_kernel(
    const float* __restrict__ x,
    const float* __restrict__ W,
    const float* __restrict__ b,
    float* __restrict__ outp,
    float* __restrict__ outi)
{
    const int row = blockIdx.x * 64 + threadIdx.x;
    double lg[64];
#pragma unroll
    for (int e = 0; e < 64; ++e) lg[e] = (double)b[e];
    const float* xr = x + (size_t)row * DDIM;
    for (int k = 0; k < DDIM; k += 4) {
        float4 xa = *reinterpret_cast<const float4*>(xr + k);
        double xd[4] = {(double)xa.x, (double)xa.y, (double)xa.z, (double)xa.w};
#pragma unroll
        for (int e = 0; e < 64; ++e) {
            const float* wp = W + (size_t)e * DDIM + k;
            double a = lg[e];
#pragma unroll
            for (int j = 0; j < 4; ++j) a = fma(xd[j], (double)wp[j], a);
            lg[e] = a;
        }
    }
    unsigned long long selm = 0ull;
    double vals[TOPK]; int idx[TOPK];
#pragma unroll
    for (int i = 0; i < TOPK; ++i) {
        double m = -DBL_MAX; int mi = 0;
#pragma unroll
        for (int e = 0; e < 64; ++e) {
            bool gt = !((selm >> e) & 1ull) && (lg[e] > m);
            m = gt ? lg[e] : m; mi = gt ? e : mi;
        }
        vals[i] = m; idx[i] = mi; selm |= (1ull << mi);
    }
    double ssum = 0.0;
#pragma unroll
    for (int i = 0; i < TOPK; ++i) ssum += exp(vals[i] - vals[0]);
    double inv = 1.0 / ssum;
#pragma unroll
    for (int e = 0; e < 64; ++e)
        outp[(size_t)row * NEXP + e] =
            ((selm >> e) & 1ull) ? (float)(exp(lg[e] - vals[0]) * inv) : 0.0f;
#pragma unroll
    for (int i = 0; i < TOPK; ++i)
        outi[(size_t)row * TOPK + i] = (float)idx[i];
}

// ---------------------------------------------------------------------------
extern "C" void kernel_launch(void* const* d_in, const int* in_sizes, int n_in,
                              void* d_out, int out_size, void* d_ws, size_t ws_size,
                              hipStream_t stream) {
    (void)in_sizes; (void)n_in; (void)out_size;
    const float* x = (const float*)d_in[0];
    const float* W = (const float*)d_in[1];
    const float* b = (const float*)d_in[2];

    float* outp = (float*)d_out;
    float* outi = outp + (size_t)NROWS * NEXP;

    const size_t wd_bytes = sizeof(double) * (size_t)NEXP * DDIM;   // 2 MB
    const size_t cnt_off  = wd_bytes;
    const size_t list_off = cnt_off + 256;
    const size_t part_off = list_off + (size_t)NROWS * sizeof(int);

    int ksbits = -1;
    for (int kb = 4; kb >= 2; --kb) {   // S = 16, 8, 4
        size_t need = part_off + ((size_t)NROWS * NEXP * sizeof(float) << kb);
        if (ws_size >= need) { ksbits = kb; break; }
    }

    if (ksbits >= 0) {
        const int S = 1 << ksbits;
        double* WdT  = (double*)d_ws;
        int*    cnt  = (int*)((char*)d_ws + cnt_off);
        int*    list = (int*)((char*)d_ws + list_off);
        float*  part = (float*)((char*)d_ws + part_off);

        prep_kernel<<<(NEXP * DDIM) / 256, 256, 0, stream>>>(W, WdT, cnt);
        gate_kernel<<<(NROWS / RB) * S, 128, 0, stream>>>(x, W, part, ksbits);
        reduce_kernel<<<NROWS / 4, 256, 0, stream>>>(part, b, outp, outi, cnt, list, S);
        fix_kernel<<<1024, 64, 0, stream>>>(x, WdT, b, outp, outi, cnt, list);
    } else {
        fallback_kernel<<<NROWS / 64, 64, 0, stream>>>(x, W, b, outp, outi);
    }
}

// Round 9
// 281.388 us; speedup vs baseline: 3.9884x; 1.2050x over previous
//
#include <hip/hip_runtime.h>
#include <cfloat>
#include <cmath>

#define NROWS 16384
#define DDIM  4096
#define NEXP  64
#define TOPK  8
#define GAP_THRESH 5e-4f

#define CHUNK  16                // k per LDS chunk
#define RB     128               // rows per block

// ws layout: [WdT 2MB][count 256B][list 64KB][part S*4MB]

// ---------------------------------------------------------------------------
// prep: WdT[k][e] = (double)W[e][k]  (fp64, transposed for coalesced fix
// loads), zero flag counter.
// ---------------------------------------------------------------------------
__global__ __launch_bounds__(256) void prep_kernel(const float* __restrict__ W,
                                                   double* __restrict__ WdT,
                                                   int* __restrict__ count) {
    int t = blockIdx.x * 256 + threadIdx.x;   // 0..262143
    int k = t >> 6, e = t & 63;
    WdT[t] = (double)W[(size_t)e * DDIM + k];
    if (t == 0) *count = 0;
}

// async 16B global->LDS (LDS dest = wave-uniform base + lane*16, linear)
__device__ __forceinline__ void gload_lds16(const float* g, float* l) {
    __builtin_amdgcn_global_load_lds(
        (const __attribute__((address_space(1))) unsigned int*)g,
        (__attribute__((address_space(3))) unsigned int*)l,
        16, 0, 0);
}

// ---------------------------------------------------------------------------
// Gate GEMM fp32.  Block = 128 thr (2 waves), tile 128 rows x 64 e.
// r9: T3/T4 counted-vmcnt schedule (m201/m218 recipe) replaces the 2-phase
// __syncthreads drain: 3-slot LDS ring (36KB -> 4 blocks/CU = 8 waves/CU),
// raw s_barrier (no drain), per-wave s_waitcnt vmcnt(12) keeps 2 stages
// (12 gload_lds) in flight across barriers.  Stage c is waited on 3 chunks
// after issue (~6000 cyc >> 900 cyc HBM) -> wait is free.
// Thread = 8 rows x 8 experts = 64 acc; per quad 16 b128 per 256 FMA.
// x read slot q^((tr>>1)&3) -> 2-way (free) + 4-way broadcast; w read slot
// q^(tc&3) -> conflict-free + 16-way broadcast.  Swizzle applied on the
// GLOBAL source (rule #21), LDS dest stays linear for global_load_lds.
// NO vmem ops in the loop besides the 6 STAGE loads (vmcnt counts depend on
// it; no spill at ~124-140 VGPR, no launch_bounds min-waves hint -- r7 bug).
// ---------------------------------------------------------------------------
__global__ __launch_bounds__(128) void gate_kernel(
    const float* __restrict__ x,
    const float* __restrict__ W,
    float* __restrict__ part,          // [S][NROWS][NEXP]
    int ksbits)
{
    __shared__ float xT[3][CHUNK * RB];    // 3 x 8 KB : 8 calls of 16 rows
    __shared__ float wT[3][CHUNK * NEXP];  // 3 x 4 KB : 4 calls of 16 experts

    const int t    = threadIdx.x;          // 0..127
    const int l    = t & 63;
    const int wv   = t >> 6;               // 0..1
    const int S    = 1 << ksbits;
    const int h    = blockIdx.x & (S - 1);
    const int row0 = (blockIdx.x >> ksbits) * RB;
    const int k0   = h << (12 - ksbits);   // h * (DDIM/S)
    const int nchunk = (DDIM >> ksbits) / CHUNK;

    const int lrow  = l >> 2;              // 0..15 row-in-call
    const int lslot = l & 3;               // 16B slot within 64B row

    // x staging: call c = wv*4+j covers rows 16c..16c+15.
    // LDS slot s of row r holds global col-group s ^ ((r>>1)&3).
    const int xcg = lslot ^ ((l >> 3) & 3);          // ((lrow>>1)&3)
    const float* gx[4];
#pragma unroll
    for (int j = 0; j < 4; ++j) {
        const int c = wv * 4 + j;
        gx[j] = x + (size_t)(row0 + c * 16 + lrow) * DDIM + k0 + xcg * 4;
    }
    // w staging: call c = wv*2+j covers experts 16c..16c+15.
    // LDS slot s of expert e holds col-group s ^ ((e>>3)&3).
    const float* gw[2];
#pragma unroll
    for (int j = 0; j < 2; ++j) {
        const int c = wv * 2 + j;
        const int wcg = lslot ^ ((2 * c + (l >> 5)) & 3);
        gw[j] = W + (size_t)(c * 16 + lrow) * DDIM + k0 + wcg * 4;
    }

#define STAGE(nb, koff) do {                                           \
        _Pragma("unroll")                                              \
        for (int j_ = 0; j_ < 4; ++j_)                                 \
            gload_lds16(gx[j_] + (koff), &xT[nb][(wv * 4 + j_) * 256]); \
        _Pragma("unroll")                                              \
        for (int j_ = 0; j_ < 2; ++j_)                                 \
            gload_lds16(gw[j_] + (koff), &wT[nb][(wv * 2 + j_) * 256]); \
    } while (0)

    // compute tile: rows tr+16*ri, experts tc*8+ei
    const int tr  = t & 15;
    const int tc  = t >> 4;                // 0..7
    const int xsw = (tr >> 1) & 3;
    const int wsw = tc & 3;
    int xo[4], wo[4];
#pragma unroll
    for (int q = 0; q < 4; ++q) {
        xo[q] = (q ^ xsw) << 2;
        wo[q] = (q ^ wsw) << 2;
    }

    float acc[8][8] = {};

#define COMPUTE(slot_) do {                                            \
        const float* xb = xT[(slot_)];                                 \
        const float* wb = wT[(slot_)];                                 \
        _Pragma("unroll")                                              \
        for (int q = 0; q < 4; ++q) {                                  \
            float4 wreg[8];                                            \
            _Pragma("unroll")                                          \
            for (int ei = 0; ei < 8; ++ei)                             \
                wreg[ei] = *reinterpret_cast<const float4*>(           \
                    wb + (tc * 8 + ei) * 16 + wo[q]);                  \
            _Pragma("unroll")                                          \
            for (int ri = 0; ri < 8; ++ri) {                           \
                float4 xv = *reinterpret_cast<const float4*>(          \
                    xb + (tr + 16 * ri) * 16 + xo[q]);                 \
                _Pragma("unroll")                                      \
                for (int ei = 0; ei < 8; ++ei) {                       \
                    acc[ri][ei] = fmaf(xv.x, wreg[ei].x, acc[ri][ei]); \
                    acc[ri][ei] = fmaf(xv.y, wreg[ei].y, acc[ri][ei]); \
                    acc[ri][ei] = fmaf(xv.z, wreg[ei].z, acc[ri][ei]); \
                    acc[ri][ei] = fmaf(xv.w, wreg[ei].w, acc[ri][ei]); \
                }                                                      \
            }                                                          \
        }                                                              \
    } while (0)

    // ---- prologue: fill the 3-slot ring (18 loads in flight) --------------
    STAGE(0, 0);
    STAGE(1, CHUNK);
    STAGE(2, 2 * CHUNK);

    // ---- main loop: counted vmcnt, drain-free barriers --------------------
    int slot = 0;
    for (int c = 0; c < nchunk - 2; ++c) {
        // retire stage c (oldest of 3 in flight), keep c+1, c+2 outstanding
        asm volatile("s_waitcnt vmcnt(12)" ::: "memory");
        __builtin_amdgcn_s_barrier();          // stage c visible to all waves
        asm volatile("" ::: "memory");
        COMPUTE(slot);
        asm volatile("" ::: "memory");
        __builtin_amdgcn_s_barrier();          // all waves done reading slot
        if (c + 3 < nchunk) STAGE(slot, (c + 3) * CHUNK);
        slot = (slot == 2) ? 0 : slot + 1;
    }
    // ---- epilogue: last two chunks ----------------------------------------
    asm volatile("s_waitcnt vmcnt(6)" ::: "memory");
    __builtin_amdgcn_s_barrier();
    asm volatile("" ::: "memory");
    COMPUTE((nchunk - 2) % 3);
    asm volatile("s_waitcnt vmcnt(0)" ::: "memory");
    __builtin_amdgcn_s_barrier();
    asm volatile("" ::: "memory");
    COMPUTE((nchunk - 1) % 3);
#undef COMPUTE
#undef STAGE

#pragma unroll
    for (int ri = 0; ri < 8; ++ri) {
        const int row = row0 + tr + 16 * ri;
        float* pp = part + ((size_t)h * NROWS + row) * NEXP + tc * 8;
        *reinterpret_cast<float4*>(pp) =
            make_float4(acc[ri][0], acc[ri][1], acc[ri][2], acc[ri][3]);
        *reinterpret_cast<float4*>(pp + 4) =
            make_float4(acc[ri][4], acc[ri][5], acc[ri][6], acc[ri][7]);
    }
}

// ---------------------------------------------------------------------------
// Reduce + top-9 + sparse softmax + ambiguity flag (proven rounds 3-8).
// S now a template constant -> unrolled, MLP-friendly h-loop.
// ---------------------------------------------------------------------------
template <int S>
__global__ __launch_bounds__(256) void reduce_kernel(
    const float* __restrict__ part,
    const float* __restrict__ b,
    float* __restrict__ outp,
    float* __restrict__ outi,
    int*   __restrict__ count,
    int*   __restrict__ list)
{
    const int lane = threadIdx.x & 63;
    const int w    = threadIdx.x >> 6;
    const int row  = blockIdx.x * 4 + w;

    float orig = b[lane];
#pragma unroll
    for (int hh = 0; hh < S; ++hh)
        orig += part[((size_t)hh * NROWS + row) * NEXP + lane];

    float cur = orig;
    float vals[9];
    float myidxf = 0.0f;
    bool  sel = false;

#pragma unroll
    for (int i = 0; i < 9; ++i) {
        float m = cur;
#pragma unroll
        for (int off = 32; off > 0; off >>= 1)
            m = fmaxf(m, __shfl_xor(m, off, 64));
        unsigned long long msk = __ballot(cur == m);
        int il = __ffsll((long long)msk) - 1;
        vals[i] = m;
        if (lane == il) { cur = -FLT_MAX; if (i < TOPK) sel = true; }
        if (i < TOPK && lane == i) myidxf = (float)il;
    }

    float ssum = 0.0f;
#pragma unroll
    for (int i = 0; i < TOPK; ++i) ssum += expf(vals[i] - vals[0]);
    float p = sel ? (expf(orig - vals[0]) / ssum) : 0.0f;

    outp[(size_t)row * NEXP + lane] = p;
    if (lane < TOPK) outi[(size_t)row * TOPK + lane] = myidxf;

    float mingap = FLT_MAX;
#pragma unroll
    for (int i = 0; i < 8; ++i) mingap = fminf(mingap, vals[i] - vals[i + 1]);
    if (lane == 0 && mingap < GAP_THRESH) {
        int pos = atomicAdd(count, 1);
        if (pos < NROWS) list[pos] = row;
    }
}

// ---------------------------------------------------------------------------
// fp64 rescue.  x row staged in LDS (coalesced float4); WdT[k][e] reads are
// wave-coalesced 512B.
// ---------------------------------------------------------------------------
__global__ __launch_bounds__(64) void fix_kernel(
    const float*  __restrict__ x,
    const double* __restrict__ WdT,
    const float*  __restrict__ b,
    float* __restrict__ outp,
    float* __restrict__ outi,
    const int* __restrict__ count,
    const int* __restrict__ list)
{
    __shared__ float xs[DDIM];
    const int lane = threadIdx.x;
    const int cnt  = *count;

    for (int i = blockIdx.x; i < cnt; i += gridDim.x) {
        const int row = list[i];

        const float4* xr4 = reinterpret_cast<const float4*>(x + (size_t)row * DDIM);
#pragma unroll
        for (int j = 0; j < DDIM / 4 / 64; ++j)
            reinterpret_cast<float4*>(xs)[j * 64 + lane] = xr4[j * 64 + lane];
        __syncthreads();

        double a0 = 0.0, a1 = 0.0, a2 = 0.0, a3 = 0.0;
        for (int k = 0; k < DDIM; k += 4) {
            float4 xv = *reinterpret_cast<const float4*>(xs + k);   // broadcast
            a0 = fma((double)xv.x, WdT[(size_t)(k + 0) * NEXP + lane], a0);
            a1 = fma((double)xv.y, WdT[(size_t)(k + 1) * NEXP + lane], a1);
            a2 = fma((double)xv.z, WdT[(size_t)(k + 2) * NEXP + lane], a2);
            a3 = fma((double)xv.w, WdT[(size_t)(k + 3) * NEXP + lane], a3);
        }
        const double orig = ((a0 + a1) + (a2 + a3)) + (double)b[lane];
        double cur = orig;

        double vals[TOPK];
        float  myidxf = 0.0f;
        bool   sel = false;

#pragma unroll
        for (int tt = 0; tt < TOPK; ++tt) {
            double m = cur;
#pragma unroll
            for (int off = 32; off > 0; off >>= 1) {
                double o = __shfl_xor(m, off, 64);
                m = fmax(m, o);
            }
            unsigned long long msk = __ballot(cur == m);
            int il = __ffsll((long long)msk) - 1;
            vals[tt] = m;
            if (lane == il) { cur = -DBL_MAX; sel = true; }
            if (lane == tt)  myidxf = (float)il;
        }

        double ssum = 0.0;
#pragma unroll
        for (int tt = 0; tt < TOPK; ++tt) ssum += exp(vals[tt] - vals[0]);
        float p = sel ? (float)(exp(orig - vals[0]) / ssum) : 0.0f;

        outp[(size_t)row * NEXP + lane] = p;
        if (lane < TOPK) outi[(size_t)row * TOPK + lane] = myidxf;
        __syncthreads();   // xs reused next iteration
    }
}

// ---------------------------------------------------------------------------
// Fallback (tiny ws): per-thread-row full fp64 from f32 W.  Correct, slow.
// ---------------------------------------------------------------------------
__global__ __launch_bounds__(64) void fallback_kernel(
    const float* __restrict__ x,
    const float* __restrict__ W,
    const float* __restrict__ b,
    float* __restrict__ outp,
    float* __restrict__ outi)
{
    const int row = blockIdx.x * 64 + threadIdx.x;
    double lg[64];
#pragma unroll
    for (int e = 0; e < 64; ++e) lg[e] = (double)b[e];
    const float* xr = x + (size_t)row * DDIM;
    for (int k = 0; k < DDIM; k += 4) {
        float4 xa = *reinterpret_cast<const float4*>(xr + k);
        double xd[4] = {(double)xa.x, (double)xa.y, (double)xa.z, (double)xa.w};
#pragma unroll
        for (int e = 0; e < 64; ++e) {
            const float* wp = W + (size_t)e * DDIM + k;
            double a = lg[e];
#pragma unroll
            for (int j = 0; j < 4; ++j) a = fma(xd[j], (double)wp[j], a);
            lg[e] = a;
        }
    }
    unsigned long long selm = 0ull;
    double vals[TOPK]; int idx[TOPK];
#pragma unroll
    for (int i = 0; i < TOPK; ++i) {
        double m = -DBL_MAX; int mi = 0;
#pragma unroll
        for (int e = 0; e < 64; ++e) {
            bool gt = !((selm >> e) & 1ull) && (lg[e] > m);
            m = gt ? lg[e] : m; mi = gt ? e : mi;
        }
        vals[i] = m; idx[i] = mi; selm |= (1ull << mi);
    }
    double ssum = 0.0;
#pragma unroll
    for (int i = 0; i < TOPK; ++i) ssum += exp(vals[i] - vals[0]);
    double inv = 1.0 / ssum;
#pragma unroll
    for (int e = 0; e < 64; ++e)
        outp[(size_t)row * NEXP + e] =
            ((selm >> e) & 1ull) ? (float)(exp(lg[e] - vals[0]) * inv) : 0.0f;
#pragma unroll
    for (int i = 0; i < TOPK; ++i)
        outi[(size_t)row * TOPK + i] = (float)idx[i];
}

// ---------------------------------------------------------------------------
extern "C" void kernel_launch(void* const* d_in, const int* in_sizes, int n_in,
                              void* d_out, int out_size, void* d_ws, size_t ws_size,
                              hipStream_t stream) {
    (void)in_sizes; (void)n_in; (void)out_size;
    const float* x = (const float*)d_in[0];
    const float* W = (const float*)d_in[1];
    const float* b = (const float*)d_in[2];

    float* outp = (float*)d_out;
    float* outi = outp + (size_t)NROWS * NEXP;

    const size_t wd_bytes = sizeof(double) * (size_t)NEXP * DDIM;   // 2 MB
    const size_t cnt_off  = wd_bytes;
    const size_t list_off = cnt_off + 256;
    const size_t part_off = list_off + (size_t)NROWS * sizeof(int);

    int ksbits = -1;
    for (int kb = 4; kb >= 2; --kb) {   // S = 16, 8, 4
        size_t need = part_off + ((size_t)NROWS * NEXP * sizeof(float) << kb);
        if (ws_size >= need) { ksbits = kb; break; }
    }

    if (ksbits >= 0) {
        const int S = 1 << ksbits;
        double* WdT  = (double*)d_ws;
        int*    cnt  = (int*)((char*)d_ws + cnt_off);
        int*    list = (int*)((char*)d_ws + list_off);
        float*  part = (float*)((char*)d_ws + part_off);

        prep_kernel<<<(NEXP * DDIM) / 256, 256, 0, stream>>>(W, WdT, cnt);
        gate_kernel<<<(NROWS / RB) * S, 128, 0, stream>>>(x, W, part, ksbits);
        if (ksbits == 4)
            reduce_kernel<16><<<NROWS / 4, 256, 0, stream>>>(part, b, outp, outi, cnt, list);
        else if (ksbits == 3)
            reduce_kernel<8><<<NROWS / 4, 256, 0, stream>>>(part, b, outp, outi, cnt, list);
        else
            reduce_kernel<4><<<NROWS / 4, 256, 0, stream>>>(part, b, outp, outi, cnt, list);
        fix_kernel<<<1024, 64, 0, stream>>>(x, WdT, b, outp, outi, cnt, list);
    } else {
        fallback_kernel<<<NROWS / 64, 64, 0, stream>>>(x, W, b, outp, outi);
    }
}